// Round 3
// baseline (4283.639 us; speedup 1.0000x reference)
//
#include <hip/hip_runtime.h>
#include <math.h>

#define B_ 64
#define T_ 32
#define N_ 128
#define SST 136    // ushort stride for 128-col split rows (+8 pad): 272 B, 16B-aligned, bank-staggered

typedef __attribute__((ext_vector_type(8))) short s8v;
typedef __attribute__((ext_vector_type(4))) float f4;

__device__ __forceinline__ float softplus_f(float v){ return (v > 20.f) ? v : log1pf(expf(v)); }
__device__ __forceinline__ float sigmoid_f(float v){ return 1.f / (1.f + expf(-v)); }
__device__ __forceinline__ float wred(float v){
#pragma unroll
    for (int o = 32; o > 0; o >>= 1) v += __shfl_down(v, o, 64);
    return v;
}
// fp32 -> bf16 hi (RN) + bf16 lo (RN of remainder)
__device__ __forceinline__ void split2(float v, unsigned short& h, unsigned short& l){
    unsigned int u  = __float_as_uint(v);
    unsigned int rh = u + 0x7fffu + ((u >> 16) & 1u);
    h = (unsigned short)(rh >> 16);
    float fh = __uint_as_float(rh & 0xffff0000u);
    float lo = v - fh;
    unsigned int ul = __float_as_uint(lo);
    unsigned int rl = ul + 0x7fffu + ((ul >> 16) & 1u);
    l = (unsigned short)(rl >> 16);
}
__device__ __forceinline__ void split4_store(float4 v, unsigned short* hp, unsigned short* lp){
    unsigned short h0,h1,h2,h3,l0,l1,l2,l3;
    split2(v.x,h0,l0); split2(v.y,h1,l1); split2(v.z,h2,l2); split2(v.w,h3,l3);
    uint2 H = make_uint2((unsigned)h0 | ((unsigned)h1 << 16), (unsigned)h2 | ((unsigned)h3 << 16));
    uint2 L = make_uint2((unsigned)l0 | ((unsigned)l1 << 16), (unsigned)l2 | ((unsigned)l3 << 16));
    *(uint2*)hp = H; *(uint2*)lp = L;
}
__device__ __forceinline__ float rec16(unsigned short h, unsigned short l){
    return __uint_as_float((unsigned)h << 16) + __uint_as_float((unsigned)l << 16);
}
__device__ __forceinline__ f4 mfma3(s8v ah, s8v al, s8v bh, s8v bl, f4 c){
    c = __builtin_amdgcn_mfma_f32_16x16x32_bf16(ah, bh, c, 0, 0, 0);
    c = __builtin_amdgcn_mfma_f32_16x16x32_bf16(ah, bl, c, 0, 0, 0);
    c = __builtin_amdgcn_mfma_f32_16x16x32_bf16(al, bh, c, 0, 0, 0);
    return c;
}

// ---- prep: split+transpose W into WT[n][l] bf16 hi/lo (n-major, l contiguous) ----
__global__ __launch_bounds__(256)
void prep_w(const float* __restrict__ Wz, const float* __restrict__ Wr,
            const float* __restrict__ Wh, unsigned short* __restrict__ WT){
    int gate = blockIdx.x, n0 = blockIdx.y * 16, tid = threadIdx.x;
    const float* W = (gate == 0) ? Wz : (gate == 1) ? Wr : Wh;
    unsigned short* hi = WT + (size_t)gate * 32768;
    unsigned short* lo = hi + 16384;
#pragma unroll
    for (int e = 0; e < 8; ++e){
        int idx = tid + e * 256;
        int n = n0 + (idx >> 7), k = idx & 127;
        float v = W[(size_t)k * 128 + n];
        unsigned short h, l; split2(v, h, l);
        hi[(size_t)n * 128 + k] = h;
        lo[(size_t)n * 128 + k] = l;
    }
}

// ---- prep: XU[g][bt][n] = x_bt . U_g  (g: 0=z,1=r,2=h), XX[bt] = ||x_bt||^2 ----
__global__ __launch_bounds__(256)
void prep_xu(const float* __restrict__ x, const float* __restrict__ Uz,
             const float* __restrict__ Ur, const float* __restrict__ Uh,
             float* __restrict__ XU, float* __restrict__ XX){
    int bt = blockIdx.x, tid = threadIdx.x;
    __shared__ float sX[128];
    __shared__ float sRed[256];
    __shared__ float sP[4];
    if (tid < 128) sX[tid] = x[(size_t)bt * 128 + tid];
    __syncthreads();
    {
        float v = (tid < 128) ? sX[tid] * sX[tid] : 0.f;
        v = wred(v);
        if ((tid & 63) == 0) sP[tid >> 6] = v;
    }
    const float* Us[3] = {Uz, Ur, Uh};
#pragma unroll 1
    for (int g = 0; g < 3; ++g){
        int n = tid & 127, hf = tid >> 7;
        float p = 0.f;
#pragma unroll 8
        for (int k = hf * 64; k < hf * 64 + 64; ++k) p = fmaf(sX[k], Us[g][(size_t)k * 128 + n], p);
        sRed[tid] = p;
        __syncthreads();
        if (tid < 128) XU[(size_t)g * (2048 * 128) + (size_t)bt * 128 + tid] = sRed[tid] + sRed[tid + 128];
        __syncthreads();
    }
    if (tid == 0) XX[bt] = sP[0] + sP[1] + sP[2] + sP[3];
}

// mm1: accP[nt] += A[rows r16*16+.] x B ; A = LDS split (AH,AL), B = WT gate plane (hi at 0, lo at +16384)
__device__ __forceinline__ void mm1_run(const unsigned short* AH, const unsigned short* AL,
                                        const unsigned short* BW, f4* accP,
                                        int r16, int c64, int q, int lm)
{
#pragma unroll
    for (int c = 0; c < 4; ++c){
        int k0 = c * 32 + q * 8;
        s8v aH = *(const s8v*)&AH[(r16 * 16 + lm) * SST + k0];
        s8v aL = *(const s8v*)&AL[(r16 * 16 + lm) * SST + k0];
#pragma unroll
        for (int nt = 0; nt < 4; ++nt){
            int j = c64 * 64 + nt * 16 + lm;
            s8v bH = *(const s8v*)&BW[j * 128 + k0];
            s8v bL = *(const s8v*)&BW[16384 + j * 128 + k0];
            accP[nt] = mfma3(aH, aL, bH, bL, accP[nt]);
        }
    }
}
__device__ __forceinline__ void pt_write(const f4* accP, unsigned short* PTh, unsigned short* PTl,
                                         int r16, int c64, int q, int lm)
{
#pragma unroll
    for (int nt = 0; nt < 4; ++nt){
        f4 a = accP[nt];
        int j = c64 * 64 + nt * 16 + lm;
        int k = r16 * 16 + q * 4;
        split4_store(make_float4(a[0], a[1], a[2], a[3]), &PTh[j * SST + k], &PTl[j * SST + k]);
    }
}
// mm2: acc2[s] += W^T x P ; A = WT gate plane (global), B = PT split (LDS)
__device__ __forceinline__ void mm2_run(const unsigned short* WA, const unsigned short* PTh,
                                        const unsigned short* PTl, f4* acc2,
                                        int c16, int r64, int q, int lm)
{
#pragma unroll
    for (int c = 0; c < 4; ++c){
        int k0 = c * 32 + q * 8;
        s8v bH = *(const s8v*)&PTh[(c16 * 16 + lm) * SST + k0];
        s8v bL = *(const s8v*)&PTl[(c16 * 16 + lm) * SST + k0];
#pragma unroll
        for (int s = 0; s < 4; ++s){
            int i = r64 * 64 + s * 16 + lm;
            s8v aH = *(const s8v*)&WA[i * 128 + k0];
            s8v aL = *(const s8v*)&WA[16384 + i * 128 + k0];
            acc2[s] = mfma3(aH, aL, bH, bL, acc2[s]);
        }
    }
}

// ---- persistent kernel: one block per batch, full T loop, S_p resident in LDS ----
__global__ __launch_bounds__(1024, 4)
void gru_persist(const float* __restrict__ Wz, const float* __restrict__ Wr,
                 const float* __restrict__ Wh,
                 const float* __restrict__ uzs, const float* __restrict__ wzs,
                 const float* __restrict__ urs, const float* __restrict__ wrs,
                 const float* __restrict__ uhs, const float* __restrict__ whs,
                 const unsigned short* __restrict__ WT,
                 const float* __restrict__ XU, const float* __restrict__ XX,
                 float* __restrict__ mu_out, float* __restrict__ S_out)
{
    const int b = blockIdx.x, tid = threadIdx.x;
    const int lane = tid & 63, w = tid >> 6, q = (tid >> 4) & 3, lm = tid & 15;
    const int r16 = w & 7, c64 = w >> 3;   // mm1 wave map: rows 16, cols 64
    const int c16 = w & 7, r64 = w >> 3;   // mm2 wave map: cols 16, rows 64

    __shared__ unsigned short sPhi[128 * SST];   // S_p hi (persistent state)
    __shared__ unsigned short sPlo[128 * SST];   // S_p lo
    __shared__ unsigned short sR2[2 * 128 * SST]; // time-multiplexed: PT_z/PT_r/S_g/PT_h (hi, lo)
    __shared__ float sMu[128], sMuN[128], sZ[128], sGz[128], sR[128], sGr[128],
                     sRh[128], sH[128], sGh[128];
    __shared__ float sSP[6][128];   // softplus(uz,wz,ur,wr,uh,wh)
    __shared__ float sRed[1024];
    __shared__ float sScal[8];

    unsigned short* PTh = sR2;
    unsigned short* PTl = sR2 + 128 * SST;
    const unsigned short* WTz = WT;
    const unsigned short* WTr = WT + 32768;
    const unsigned short* WTh = WT + 65536;

    for (int i = tid; i < 128 * SST; i += 1024){ sPhi[i] = 0; sPlo[i] = 0; }
    if (tid < 128) sMu[tid] = 0.f;
    if (tid < 768){
        int tb = tid >> 7, n = tid & 127;
        const float* src = (tb == 0) ? uzs : (tb == 1) ? wzs : (tb == 2) ? urs :
                           (tb == 3) ? wrs : (tb == 4) ? uhs : whs;
        sSP[tb][n] = softplus_f(src[n]);
    }
    __syncthreads();

    float szv[4][4];   // S_z register tile (mm2 positions)
    float sgv[4][4];   // S_g stash between r-epilogue and LDS publish

#pragma unroll 1
    for (int t = 0; t < T_; ++t){
        const int bt = b * T_ + t;

        // ---- phase A: scalars + gate vectors ----
        if (tid < 128){
            float mu = sMu[tid];
            float v1 = mu * mu;
            float v2 = rec16(sPhi[tid * SST + tid], sPlo[tid * SST + tid]);
            v1 = wred(v1); v2 = wred(v2);
            if (lane == 0){ sScal[w * 2] = v1; sScal[w * 2 + 1] = v2; }
        }
        {
            int g = tid >> 9, n = tid & 127, seg = (tid >> 7) & 3;
            const float* Wg = g ? Wr : Wz;
            float p = 0.f;
#pragma unroll
            for (int k = seg * 32; k < seg * 32 + 32; ++k) p = fmaf(sMu[k], Wg[k * N_ + n], p);
            sRed[tid] = p;
        }
        __syncthreads();
        if (tid < 256){
            int g = tid >> 7, n = tid & 127;
            float a = XU[(size_t)g * 262144 + (size_t)bt * 128 + n];
            a += sRed[g * 512 + n] + sRed[g * 512 + 128 + n]
               + sRed[g * 512 + 256 + n] + sRed[g * 512 + 384 + n];
            float gg = sigmoid_f(a);
            if (!g){ sZ[n] = gg; sGz[n] = gg * (1.f - gg); }
            else   { sR[n] = gg; sGr[n] = gg * (1.f - gg); }
        }
        __syncthreads();
        if (tid < 128){
            float rh = sMu[tid] * sR[tid]; sRh[tid] = rh;
            float v = rh * rh; v = wred(v);
            if (lane == 0) sScal[4 + w] = v;
        }
        __syncthreads();
        {
            int n = tid & 127, seg = tid >> 7;
            float p = 0.f;
#pragma unroll
            for (int k = seg * 16; k < seg * 16 + 16; ++k) p = fmaf(sRh[k], Wh[k * N_ + n], p);
            sRed[tid] = p;
        }
        __syncthreads();
        if (tid < 128){
            float a = XU[(size_t)2 * 262144 + (size_t)bt * 128 + tid];
#pragma unroll
            for (int s = 0; s < 8; ++s) a += sRed[s * 128 + tid];
            float h = tanhf(a);
            sH[tid] = h; sGh[tid] = 1.f - h * h;
            float z = sZ[tid];
            float mun = z * sMu[tid] + (1.f - z) * h;
            sMuN[tid] = mun;
            mu_out[(size_t)bt * 128 + tid] = mun;
        }
        __syncthreads();

        const float xx = XX[bt];
        const float pt = sScal[0] + sScal[2] + sScal[1] + sScal[3];  // pp + trS
        const float rr = sScal[4] + sScal[5];

        // ---- z sandwich ----
        f4 accP[4], acc2[4];
#pragma unroll
        for (int i = 0; i < 4; ++i) accP[i] = (f4){0.f, 0.f, 0.f, 0.f};
        mm1_run(sPhi, sPlo, WTz, accP, r16, c64, q, lm);
        pt_write(accP, PTh, PTl, r16, c64, q, lm);
        __syncthreads();
#pragma unroll
        for (int i = 0; i < 4; ++i) acc2[i] = (f4){0.f, 0.f, 0.f, 0.f};
        mm2_run(WTz, PTh, PTl, acc2, c16, r64, q, lm);
#pragma unroll
        for (int s = 0; s < 4; ++s)
#pragma unroll
            for (int r = 0; r < 4; ++r){
                int i = r64 * 64 + s * 16 + q * 4 + r;
                int j = c16 * 16 + lm;
                float v = acc2[s][r];
                if (i == j) v += pt * sSP[1][i] + xx * sSP[0][i];
                szv[s][r] = v * sGz[i] * sGz[j];
            }

        // ---- r sandwich (mm1 overlaps PT_z lifetime: reads only sPhi/sPlo) ----
#pragma unroll
        for (int i = 0; i < 4; ++i) accP[i] = (f4){0.f, 0.f, 0.f, 0.f};
        mm1_run(sPhi, sPlo, WTr, accP, r16, c64, q, lm);
        __syncthreads();                    // PT_z reads done
        pt_write(accP, PTh, PTl, r16, c64, q, lm);
        __syncthreads();
#pragma unroll
        for (int i = 0; i < 4; ++i) acc2[i] = (f4){0.f, 0.f, 0.f, 0.f};
        mm2_run(WTr, PTh, PTl, acc2, c16, r64, q, lm);
        float tdiag = 0.f;
#pragma unroll
        for (int s = 0; s < 4; ++s)
#pragma unroll
            for (int r = 0; r < 4; ++r){
                int i = r64 * 64 + s * 16 + q * 4 + r;
                int j = c16 * 16 + lm;
                float v = acc2[s][r];
                if (i == j) v += pt * sSP[3][i] + xx * sSP[2][i];
                float sr = v * sGr[i] * sGr[j];
                float sp = rec16(sPhi[i * SST + j], sPlo[i * SST + j]);
                float sg = sr * (sp + sMu[i] * sMu[j]) + sR[i] * sR[j] * sp;
                if (i == j) tdiag += sg;
                sgv[s][r] = sg;
            }
        __syncthreads();                    // PT_r reads done -> R2 becomes S_g
#pragma unroll
        for (int s = 0; s < 4; ++s)
#pragma unroll
            for (int r = 0; r < 4; ++r){
                int i = r64 * 64 + s * 16 + q * 4 + r;
                int j = c16 * 16 + lm;
                unsigned short hh, ll; split2(sgv[s][r], hh, ll);
                PTh[i * SST + j] = hh;
                PTl[i * SST + j] = ll;
            }
        {
            float td = wred(tdiag);
            if (lane == 0) sRed[w] = td;
        }
        __syncthreads();                    // S_g published

        // ---- h sandwich ----
#pragma unroll
        for (int i = 0; i < 4; ++i) accP[i] = (f4){0.f, 0.f, 0.f, 0.f};
        mm1_run(PTh, PTl, WTh, accP, r16, c64, q, lm);
        __syncthreads();                    // S_g reads done -> R2 becomes PT_h
        pt_write(accP, PTh, PTl, r16, c64, q, lm);
        __syncthreads();
#pragma unroll
        for (int i = 0; i < 4; ++i) acc2[i] = (f4){0.f, 0.f, 0.f, 0.f};
        mm2_run(WTh, PTh, PTl, acc2, c16, r64, q, lm);

        // ---- final combine, output write, in-place S_p update ----
        float trg = 0.f;
#pragma unroll
        for (int i = 0; i < 16; ++i) trg += sRed[i];
        const float coef = rr + trg;
        float* outS = S_out + (size_t)bt * 16384;
#pragma unroll
        for (int s = 0; s < 4; ++s)
#pragma unroll
            for (int r = 0; r < 4; ++r){
                int i = r64 * 64 + s * 16 + q * 4 + r;
                int j = c16 * 16 + lm;
                float shh = acc2[s][r];
                if (i == j) shh += coef * sSP[5][i] + xx * sSP[4][i];
                float sh = shh * sGh[i] * sGh[j];
                float sp = rec16(sPhi[i * SST + j], sPlo[i * SST + j]);
                float sz = szv[s][r];
                float dmi = sMu[i] - sH[i], dmj = sMu[j] - sH[j];
                float zi = sZ[i], zj = sZ[j];
                float sv = sz * (sp + sh + dmi * dmj) + zi * zj * sp
                         + (1.f - zi) * (1.f - zj) * sh;
                if (!isfinite(sv)) sv = 0.f;
                if (i == j) sv = fabsf(sv);
                outS[(size_t)i * 128 + j] = sv;
                unsigned short hh, ll; split2(sv, hh, ll);
                sPhi[i * SST + j] = hh;
                sPlo[i * SST + j] = ll;
            }
        __syncthreads();
        if (tid < 128) sMu[tid] = sMuN[tid];
        __syncthreads();
    }
}

extern "C" void kernel_launch(void* const* d_in, const int* in_sizes, int n_in,
                              void* d_out, int out_size, void* d_ws, size_t ws_size,
                              hipStream_t stream)
{
    (void)in_sizes; (void)n_in; (void)out_size; (void)ws_size;
    const float* x   = (const float*)d_in[0];
    const float* Uz  = (const float*)d_in[1];
    const float* Wz  = (const float*)d_in[2];
    const float* Ur  = (const float*)d_in[3];
    const float* Wr  = (const float*)d_in[4];
    const float* Uh  = (const float*)d_in[5];
    const float* Wh  = (const float*)d_in[6];
    const float* uzs = (const float*)d_in[7];
    const float* wzs = (const float*)d_in[8];
    const float* urs = (const float*)d_in[9];
    const float* wrs = (const float*)d_in[10];
    const float* uhs = (const float*)d_in[11];
    const float* whs = (const float*)d_in[12];

    float* mu_out = (float*)d_out;
    float* S_out  = (float*)d_out + (size_t)B_ * T_ * N_;

    char* ws = (char*)d_ws;
    unsigned short* wsWT = (unsigned short*)ws;        // 6 planes x 16384 ushort = 196608 B
    float* wsXU = (float*)(ws + 196608);               // 3 x 2048 x 128 f32
    float* wsXX = (float*)(ws + 3342336);              // 2048 f32

    hipLaunchKernelGGL(prep_w, dim3(3, 8), dim3(256), 0, stream, Wz, Wr, Wh, wsWT);
    hipLaunchKernelGGL(prep_xu, dim3(2048), dim3(256), 0, stream, x, Uz, Ur, Uh, wsXU, wsXX);
    hipLaunchKernelGGL(gru_persist, dim3(B_), dim3(1024), 0, stream,
                       Wz, Wr, Wh, uzs, wzs, urs, wrs, uhs, whs,
                       wsWT, wsXU, wsXX, mu_out, S_out);
}